// Round 14
// baseline (1376.828 us; speedup 1.0000x reference)
//
#include <hip/hip_runtime.h>
#include <hip/hip_bf16.h>

typedef unsigned short u16;
typedef unsigned int u32;
typedef __bf16 bf16x8 __attribute__((ext_vector_type(8)));
typedef float f32x4 __attribute__((ext_vector_type(4)));

#define DEV static __device__ __forceinline__
#define GPTR(p) (const __attribute__((address_space(1))) u32*)(p)
#define LPTR(p) (__attribute__((address_space(3))) u32*)(p)

DEV float bf2f(u16 u) { return __uint_as_float((u32)u << 16); }
DEV u16 f2bf(float f) {
  u32 x = __float_as_uint(f);
  x += 0x7fffu + ((x >> 16) & 1u);
  return (u16)(x >> 16);
}
DEV u32 pk2(float a, float b) { return (u32)f2bf(a) | ((u32)f2bf(b) << 16); }
DEV float gelu_f(float x) { return 0.5f * x * (1.0f + erff(x * 0.70710678118654752440f)); }

// transpose h0_w1 (64,1024) -> (1024,64) f32
__global__ void w1t_k(const float* __restrict__ w1, float* __restrict__ w1t) {
  int i = blockIdx.x * 256 + threadIdx.x;
  if (i < 64 * 1024) {
    int o = i >> 10, c = i & 1023;
    w1t[c * 64 + o] = w1[i];
  }
}

// ---------------------------------------------------------------- LayerNorm (row per WAVE)
// 4 rows/block, row in registers, shfl_xor reduce, no LDS.  (r12-proven)
template<int DIM, int OUTM, int INBF>
__global__ __launch_bounds__(256) void ln_k(const void* __restrict__ inp,
                                            const float* __restrict__ g,
                                            const float* __restrict__ b,
                                            void* __restrict__ outp) {
  constexpr int NG = DIM / 512;   // 8-elem groups per lane
  const int w = threadIdx.x >> 6, lane = threadIdx.x & 63;
  const int row = blockIdx.x * 4 + w;
  float v[NG * 8];
  if (INBF == 1) {
    const u16* in = (const u16*)inp + (size_t)row * DIM;
#pragma unroll
    for (int i = 0; i < NG; ++i) {
      uint4 u = ((const uint4*)in)[i * 64 + lane];
      const u16* e = (const u16*)&u;
#pragma unroll
      for (int t = 0; t < 8; ++t) v[i * 8 + t] = bf2f(e[t]);
    }
  } else {
    const float* in = (const float*)inp + (size_t)row * DIM;
#pragma unroll
    for (int i = 0; i < NG; ++i)
#pragma unroll
      for (int h = 0; h < 2; ++h) {
        float4 f = ((const float4*)in)[i * 128 + h * 64 + lane];
        v[i * 8 + h * 4 + 0] = f.x; v[i * 8 + h * 4 + 1] = f.y;
        v[i * 8 + h * 4 + 2] = f.z; v[i * 8 + h * 4 + 3] = f.w;
      }
  }
  float s = 0.f, s2 = 0.f;
#pragma unroll
  for (int t = 0; t < NG * 8; ++t) { s += v[t]; s2 += v[t] * v[t]; }
#pragma unroll
  for (int d = 1; d < 64; d <<= 1) { s += __shfl_xor(s, d); s2 += __shfl_xor(s2, d); }
  const float mean = s / DIM;
  const float rstd = rsqrtf(s2 / DIM - mean * mean + 1e-5f);

  if (INBF == 1) {
#pragma unroll
    for (int i = 0; i < NG; ++i) {
      const int u8 = i * 64 + lane;
      float o[8];
#pragma unroll
      for (int h = 0; h < 2; ++h) {
        float4 gv = ((const float4*)g)[u8 * 2 + h];
        float4 bv = ((const float4*)b)[u8 * 2 + h];
        o[h * 4 + 0] = (v[i * 8 + h * 4 + 0] - mean) * rstd * gv.x + bv.x;
        o[h * 4 + 1] = (v[i * 8 + h * 4 + 1] - mean) * rstd * gv.y + bv.y;
        o[h * 4 + 2] = (v[i * 8 + h * 4 + 2] - mean) * rstd * gv.z + bv.z;
        o[h * 4 + 3] = (v[i * 8 + h * 4 + 3] - mean) * rstd * gv.w + bv.w;
      }
      if (OUTM == 0) {
        uint4 u;
        u.x = pk2(o[0], o[1]); u.y = pk2(o[2], o[3]);
        u.z = pk2(o[4], o[5]); u.w = pk2(o[6], o[7]);
        ((uint4*)((u16*)outp + (size_t)row * DIM))[u8] = u;
      } else {
        float* orow = (float*)outp + (size_t)row * DIM;
#pragma unroll
        for (int h = 0; h < 2; ++h)
          ((float4*)orow)[u8 * 2 + h] =
              make_float4(o[h * 4 + 0], o[h * 4 + 1], o[h * 4 + 2], o[h * 4 + 3]);
      }
    }
  } else {
#pragma unroll
    for (int i = 0; i < NG; ++i) {
#pragma unroll
      for (int h = 0; h < 2; ++h) {
        const int u4 = i * 128 + h * 64 + lane;
        float4 gv = ((const float4*)g)[u4];
        float4 bv = ((const float4*)b)[u4];
        float o0 = (v[i * 8 + h * 4 + 0] - mean) * rstd * gv.x + bv.x;
        float o1 = (v[i * 8 + h * 4 + 1] - mean) * rstd * gv.y + bv.y;
        float o2 = (v[i * 8 + h * 4 + 2] - mean) * rstd * gv.z + bv.z;
        float o3 = (v[i * 8 + h * 4 + 3] - mean) * rstd * gv.w + bv.w;
        if (OUTM == 0) {
          ushort4 u;
          u.x = f2bf(o0); u.y = f2bf(o1); u.z = f2bf(o2); u.w = f2bf(o3);
          ((ushort4*)((u16*)outp + (size_t)row * DIM))[u4] = u;
        } else {
          ((float4*)((float*)outp + (size_t)row * DIM))[u4] = make_float4(o0, o1, o2, o3);
        }
      }
    }
  }
}

// ---------------------------------------------------------------- bf16-A x f32-B NT GEMM
// C[m,n] = sum_k A[m,k] * bf16(B[n,k]) + bias[n]   (r3/r8-proven loop structure)
// A (bf16 activations): global_load_lds DMA, both-sides XOR swizzle (0 conflicts).
// B (f32 weights): converted IN the staging path — 2x float4 loads issued right
// after the barrier (latency hides under MFMA, like the A-DMA), pk-packed to
// bf16, ds_write_b128 to the IDENTICAL LDS slot the DMA used.  Byte-identical
// LDS image -> MFMA side untouched.  Top-of-loop vmcnt(0)+lgkmcnt(0)+barrier
// drains each wave's DMA AND ds_writes before anyone reads.  This removes the
// separate 90us f32->bf16 weight-conversion pass entirely.
// EPI (all bf16 out): 0 = gelu, 1 = plain, 2 = residual add in-place, 3 = relu
template<int EPI, int BN>
__global__ __launch_bounds__(512, BN == 64 ? 6 : 4)
void gemm_bt(const u16* __restrict__ A,
             const float* __restrict__ B,
             const float* __restrict__ bias,
             u16* __restrict__ Cb,
             int N, int K, int nx) {
  constexpr int WC = BN / 32;               // waves along N
  constexpr int MR = (128 * WC / 8) / 16;   // 16-row frags per wave along M
  constexpr int BC = BN / 64;               // B chunks per wave
  __shared__ u16 As[2][128 * 64];
  __shared__ u16 Bs[2][BN * 64];
  const int tid = threadIdx.x;
  const int nwg = gridDim.x;
  const int bid = blockIdx.x;
  const int swz = (bid & 7) * (nwg >> 3) + (bid >> 3);  // nwg % 8 == 0 always here
  const int by = swz / nx, bx = swz - by * nx;
  const int brow = by * 128, bcol = bx * BN;
  const int lane = tid & 63, w = tid >> 6;
  const int wr = (w / WC) * (MR * 16), wc = (w % WC) * 32;
  const int fr = lane & 15, fg = lane >> 4;
  const int swb = (fr & 7) << 4;            // read-side XOR (bytes within 128B row)
  const int ldr = lane >> 3;                // row within 8-row staging chunk
  const int lc8 = lane & 7;                 // 16B slot
  const int cs8 = (lc8 ^ ldr) * 8;          // inverse-swizzled source column (elems)

  const u16* Ab = A + (size_t)(brow + ldr) * K + cs8;
  const float* Bb = B + (size_t)(bcol + ldr) * K + cs8;

  f32x4 acc[MR][2];
  const f32x4 z = {0.f, 0.f, 0.f, 0.f};
#pragma unroll
  for (int m = 0; m < MR; ++m) { acc[m][0] = z; acc[m][1] = z; }

  f32x4 breg[BC][2];

  auto stageA = [&](int kt, int buf) {
    const int k0 = kt << 6;
#pragma unroll
    for (int i = 0; i < 2; ++i) {
      const int c = i * 8 + w;
      __builtin_amdgcn_global_load_lds(GPTR(Ab + (size_t)c * 8 * K + k0),
                                       LPTR(&As[buf][c * 512 + lane * 8]), 16, 0, 0);
    }
  };
  auto loadB = [&](int kt) {
    const int k0 = kt << 6;
#pragma unroll
    for (int i = 0; i < BC; ++i) {
      const int c = i * 8 + w;
      const float* p = Bb + (size_t)c * 8 * K + k0;
      breg[i][0] = *(const f32x4*)p;
      breg[i][1] = *(const f32x4*)(p + 4);
    }
  };
  auto writeB = [&](int buf) {
#pragma unroll
    for (int i = 0; i < BC; ++i) {
      const int c = i * 8 + w;
      uint4 o;
      o.x = pk2(breg[i][0][0], breg[i][0][1]);
      o.y = pk2(breg[i][0][2], breg[i][0][3]);
      o.z = pk2(breg[i][1][0], breg[i][1][1]);
      o.w = pk2(breg[i][1][2], breg[i][1][3]);
      *(uint4*)&Bs[buf][c * 512 + lane * 8] = o;
    }
  };

  loadB(0);
  stageA(0, 0);
  writeB(0);
  const int nkt = K >> 6;
  for (int kt = 0; kt < nkt; ++kt) {
    const int buf = kt & 1;
    asm volatile("s_waitcnt vmcnt(0) lgkmcnt(0)" ::: "memory");
    __builtin_amdgcn_s_barrier();
    __builtin_amdgcn_sched_barrier(0);
    if (kt + 1 < nkt) { loadB(kt + 1); stageA(kt + 1, buf ^ 1); }
    const char* Asb = (const char*)&As[buf][0];
    const char* Bsb = (const char*)&Bs[buf][0];
    __builtin_amdgcn_s_setprio(1);
#pragma unroll
    for (int ks = 0; ks < 2; ++ks) {
      bf16x8 af[MR], bfr[2];
      const int cb = (ks * 64 + fg * 16) ^ swb;
#pragma unroll
      for (int m = 0; m < MR; ++m)
        af[m] = *(const bf16x8*)(Asb + (wr + m * 16 + fr) * 128 + cb);
#pragma unroll
      for (int n = 0; n < 2; ++n)
        bfr[n] = *(const bf16x8*)(Bsb + (wc + n * 16 + fr) * 128 + cb);
#pragma unroll
      for (int m = 0; m < MR; ++m)
#pragma unroll
        for (int n = 0; n < 2; ++n)
          acc[m][n] = __builtin_amdgcn_mfma_f32_16x16x32_bf16(af[m], bfr[n], acc[m][n], 0, 0, 0);
    }
    __builtin_amdgcn_s_setprio(0);
    if (kt + 1 < nkt) writeB(buf ^ 1);
  }

#pragma unroll
  for (int n = 0; n < 2; ++n) {
    const int col = bcol + wc + n * 16 + fr;
    const float bv = bias[col];
#pragma unroll
    for (int m = 0; m < MR; ++m) {
      const int row0 = brow + wr + m * 16 + fg * 4;
#pragma unroll
      for (int j = 0; j < 4; ++j) {
        float v = acc[m][n][j] + bv;
        const size_t idx = (size_t)(row0 + j) * N + col;
        if (EPI == 0) Cb[idx] = f2bf(gelu_f(v));
        else if (EPI == 1) Cb[idx] = f2bf(v);
        else if (EPI == 2) Cb[idx] = f2bf(bf2f(Cb[idx]) + v);
        else Cb[idx] = f2bf(fmaxf(v, 0.f));
      }
    }
  }
}

// ---------------------------------------------------------------- MFMA attention (r11-proven)
__global__ __launch_bounds__(128) void attn_k(const u16* __restrict__ qkv,
                                              u16* __restrict__ o) {
  __shared__ u16 lds[2][12672];   // per wave: Vt[128][72] (9216) + P[48][72] (3456)
  const int tid = threadIdx.x, w = tid >> 6, l = tid & 63;
  const int b = blockIdx.x >> 2, hp = blockIdx.x & 3;
  const int h = hp * 2 + w;
  u16* Vt = &lds[w][0];
  u16* P  = &lds[w][9216];
  const int fr = l & 15, fg = l >> 4;
  const size_t qbase = (size_t)b * 36 * 3072 + h * 128;
  const size_t kbase = qbase + 1024;
  const size_t vbase = qbase + 2048;

  for (int i = l; i < 1584; i += 64) {
    uint4 zz = {0u, 0u, 0u, 0u};
    *(uint4*)&lds[w][i * 8] = zz;
  }

  for (int i = l; i < 576; i += 64) {
    const int k = i >> 4, nc = (i & 15) * 8;
    uint4 u = *(const uint4*)&qkv[vbase + (size_t)k * 3072 + nc];
    const u16* e = (const u16*)&u;
#pragma unroll
    for (int t = 0; t < 8; ++t) Vt[(nc + t) * 72 + k] = e[t];
  }

  const f32x4 z = {0.f, 0.f, 0.f, 0.f};
  f32x4 S[3][3];
#pragma unroll
  for (int mt = 0; mt < 3; ++mt)
#pragma unroll
    for (int nt = 0; nt < 3; ++nt) S[mt][nt] = z;
#pragma unroll
  for (int ks = 0; ks < 4; ++ks) {
    bf16x8 qa[3], kb[3];
#pragma unroll
    for (int mt = 0; mt < 3; ++mt) {
      const int r = min(mt * 16 + fr, 35);
      qa[mt] = *(const bf16x8*)&qkv[qbase + (size_t)r * 3072 + ks * 32 + fg * 8];
      kb[mt] = *(const bf16x8*)&qkv[kbase + (size_t)r * 3072 + ks * 32 + fg * 8];
    }
#pragma unroll
    for (int mt = 0; mt < 3; ++mt)
#pragma unroll
      for (int nt = 0; nt < 3; ++nt)
        S[mt][nt] = __builtin_amdgcn_mfma_f32_16x16x32_bf16(qa[mt], kb[nt], S[mt][nt], 0, 0, 0);
  }

  const float sc = 0.08838834764831845f;
#pragma unroll
  for (int mt = 0; mt < 3; ++mt) {
#pragma unroll
    for (int j = 0; j < 4; ++j) {
      float v0 = S[mt][0][j] * sc;
      float v1 = S[mt][1][j] * sc;
      float v2 = (fr >= 4) ? -1e30f : S[mt][2][j] * sc;
      float m = fmaxf(fmaxf(v0, v1), v2);
#pragma unroll
      for (int d = 1; d < 16; d <<= 1) m = fmaxf(m, __shfl_xor(m, d));
      float e0 = __expf(v0 - m);
      float e1 = __expf(v1 - m);
      float e2 = (fr >= 4) ? 0.f : __expf(v2 - m);
      float sum = e0 + e1 + e2;
#pragma unroll
      for (int d = 1; d < 16; d <<= 1) sum += __shfl_xor(sum, d);
      const float inv = 1.f / sum;
      const int r = mt * 16 + fg * 4 + j;
      P[r * 72 + fr]      = f2bf(e0 * inv);
      P[r * 72 + 16 + fr] = f2bf(e1 * inv);
      P[r * 72 + 32 + fr] = f2bf(e2 * inv);
    }
  }

#pragma unroll
  for (int g = 0; g < 2; ++g) {
    f32x4 O[3][4];
#pragma unroll
    for (int mt = 0; mt < 3; ++mt)
#pragma unroll
      for (int nt = 0; nt < 4; ++nt) O[mt][nt] = z;
#pragma unroll
    for (int ks = 0; ks < 2; ++ks) {
      bf16x8 pa[3], vb[4];
#pragma unroll
      for (int mt = 0; mt < 3; ++mt)
        pa[mt] = *(const bf16x8*)&P[(mt * 16 + fr) * 72 + ks * 32 + fg * 8];
#pragma unroll
      for (int nt = 0; nt < 4; ++nt)
        vb[nt] = *(const bf16x8*)&Vt[((g * 4 + nt) * 16 + fr) * 72 + ks * 32 + fg * 8];
#pragma unroll
      for (int mt = 0; mt < 3; ++mt)
#pragma unroll
        for (int nt = 0; nt < 4; ++nt)
          O[mt][nt] = __builtin_amdgcn_mfma_f32_16x16x32_bf16(pa[mt], vb[nt], O[mt][nt], 0, 0, 0);
    }
#pragma unroll
    for (int mt = 0; mt < 3; ++mt) {
#pragma unroll
      for (int j = 0; j < 4; ++j) {
        const int r = mt * 16 + fg * 4 + j;
        if (r < 36) {
#pragma unroll
          for (int nt = 0; nt < 4; ++nt)
            o[((size_t)b * 36 + r) * 1024 + h * 128 + g * 64 + nt * 16 + fr] =
                f2bf(O[mt][nt][j]);
        }
      }
    }
  }
}

// ---------------------------------------------------------------- attention-map head (r9-proven)
__global__ __launch_bounds__(256) void h0_k(const u16* __restrict__ xr,
                                            const float* __restrict__ w1t,
                                            const float* __restrict__ b1,
                                            const float* __restrict__ w2,
                                            const float* __restrict__ b2v,
                                            float* __restrict__ full) {
  __shared__ float xs[8][1024];  // 32 KB
  const int t0 = blockIdx.x * 8, tid = threadIdx.x;
#pragma unroll
  for (int i = 0; i < 8; ++i) {
    const int idx = tid + i * 256;
    const int t = idx >> 8, c4 = idx & 255;
    ushort4 u = ((const ushort4*)(xr + (size_t)(t0 + t) * 1024))[c4];
    xs[t][c4 * 4 + 0] = bf2f(u.x);
    xs[t][c4 * 4 + 1] = bf2f(u.y);
    xs[t][c4 * 4 + 2] = bf2f(u.z);
    xs[t][c4 * 4 + 3] = bf2f(u.w);
  }
  __syncthreads();
  const int w = tid >> 6, lane = tid & 63;
  float s0 = 0.f, s1 = 0.f;
  for (int c = 0; c < 1024; ++c) {
    const float wv = w1t[c * 64 + lane];
    s0 = fmaf(xs[w * 2 + 0][c], wv, s0);
    s1 = fmaf(xs[w * 2 + 1][c], wv, s1);
  }
  const float bb = b1[lane], wo = w2[lane];
  float v0 = gelu_f(s0 + bb) * wo;
  float v1 = gelu_f(s1 + bb) * wo;
#pragma unroll
  for (int off = 32; off; off >>= 1) {
    v0 += __shfl_down(v0, off);
    v1 += __shfl_down(v1, off);
  }
  if (lane == 0) {
    full[t0 + w * 2 + 0] = v0 + b2v[0];
    full[t0 + w * 2 + 1] = v1 + b2v[0];
  }
}

__global__ void am2_k(const float* __restrict__ full, const float* __restrict__ temp,
                      float* __restrict__ out) {
  const int i = blockIdx.x * 256 + threadIdx.x;
  if (i < 128 * 36 * 35) {
    const int j = i % 35;
    const int t = i / 35;
    const int p = t % 36;
    const int b = t / 36;
    const int col = j + (j >= p ? 1 : 0);
    const float v = full[b * 36 + col] / temp[0];
    out[i] = 1.f / (1.f + expf(-v));
  }
}

// ---------------------------------------------------------------- launch
extern "C" void kernel_launch(void* const* d_in, const int* in_sizes, int n_in,
                              void* d_out, int out_size, void* d_ws, size_t ws_size,
                              hipStream_t stream) {
  const float* x     = (const float*)d_in[0];
  const float* ln0_g = (const float*)d_in[1];
  const float* ln0_b = (const float*)d_in[2];
  const float* Wred  = (const float*)d_in[3];
  const float* bred  = (const float*)d_in[4];
  const float* h0_w1 = (const float*)d_in[5];
  const float* h0_b1 = (const float*)d_in[6];
  const float* h0_w2 = (const float*)d_in[7];
  const float* h0_b2 = (const float*)d_in[8];
  const float* temp  = (const float*)d_in[9];
  const float* Wqkv  = (const float*)d_in[10];
  const float* bqkv  = (const float*)d_in[11];
  const float* Wo    = (const float*)d_in[12];
  const float* bo    = (const float*)d_in[13];
  const float* ln1_g = (const float*)d_in[14];
  const float* ln1_b = (const float*)d_in[15];
  const float* W1    = (const float*)d_in[16];
  const float* b1    = (const float*)d_in[17];
  const float* W2    = (const float*)d_in[18];
  const float* b2    = (const float*)d_in[19];
  const float* ln2_g = (const float*)d_in[20];
  const float* ln2_b = (const float*)d_in[21];
  const float* lnf_g = (const float*)d_in[22];
  const float* lnf_b = (const float*)d_in[23];

  char* ws = (char*)d_ws;
  size_t off = 0;
  auto alloc = [&](size_t bytes) -> void* {
    void* p = ws + off;
    off += (bytes + 255) & ~(size_t)255;
    return p;
  };
  float* w1t  = (float*)alloc((size_t)1024 * 64 * 4);
  u16* yb     = (u16*)alloc((size_t)4608 * 1024 * 2);   // residual stream (bf16)
  u16* big    = (u16*)alloc((size_t)4608 * 3072 * 2);   // xn / qkv / f
  u16* nbuf   = (u16*)alloc((size_t)4608 * 1024 * 2);   // ynorm / o
  float* fullb = (float*)alloc((size_t)4608 * 4);

  w1t_k<<<64 * 1024 / 256, 256, 0, stream>>>(h0_w1, w1t);

  // dim reduce: xr = gelu(LN0(x) @ Wred^T + bred) -> yb (bf16)
  ln_k<3072, 0, 0><<<1152, 256, 0, stream>>>(x, ln0_g, ln0_b, big);
  gemm_bt<0, 64><<<16 * 36, 512, 0, stream>>>(big, Wred, bred, yb, 1024, 3072, 16);
  // attention maps head
  h0_k<<<576, 256, 0, stream>>>(yb, w1t, h0_b1, h0_w2, h0_b2, fullb);
  am2_k<<<(128 * 36 * 35 + 255) / 256, 256, 0, stream>>>(fullb, temp,
                                                         (float*)d_out + 4608 * 1024);

  for (int l = 0; l < 6; ++l) {
    ln_k<1024, 0, 1><<<1152, 256, 0, stream>>>(yb, ln1_g + l * 1024, ln1_b + l * 1024, nbuf);
    gemm_bt<1, 128><<<24 * 36, 512, 0, stream>>>(nbuf, Wqkv + (size_t)l * 3072 * 1024,
                                                 bqkv + l * 3072, big, 3072, 1024, 24);
    attn_k<<<128 * 4, 128, 0, stream>>>(big, nbuf);
    gemm_bt<2, 64><<<16 * 36, 512, 0, stream>>>(nbuf, Wo + (size_t)l * 1024 * 1024,
                                                bo + l * 1024, yb, 1024, 1024, 16);
    ln_k<1024, 0, 1><<<1152, 256, 0, stream>>>(yb, ln2_g + l * 1024, ln2_b + l * 1024, nbuf);
    gemm_bt<3, 128><<<16 * 36, 512, 0, stream>>>(nbuf, W1 + (size_t)l * 2048 * 1024,
                                                 b1 + l * 2048, big, 2048, 1024, 16);
    gemm_bt<2, 64><<<16 * 36, 512, 0, stream>>>(big, W2 + (size_t)l * 1024 * 2048,
                                                b2 + l * 1024, yb, 1024, 2048, 16);
  }
  ln_k<1024, 1, 1><<<1152, 256, 0, stream>>>(yb, lnf_g, lnf_b, d_out);
}

// Round 15
// 1076.301 us; speedup vs baseline: 1.2792x; 1.2792x over previous
//
#include <hip/hip_runtime.h>
#include <hip/hip_bf16.h>

typedef unsigned short u16;
typedef unsigned int u32;
typedef __bf16 bf16x8 __attribute__((ext_vector_type(8)));
typedef float f32x4 __attribute__((ext_vector_type(4)));

#define DEV static __device__ __forceinline__
#define GPTR(p) (const __attribute__((address_space(1))) u32*)(p)
#define LPTR(p) (__attribute__((address_space(3))) u32*)(p)

DEV float bf2f(u16 u) { return __uint_as_float((u32)u << 16); }
DEV u16 f2bf(float f) {
  u32 x = __float_as_uint(f);
  x += 0x7fffu + ((x >> 16) & 1u);
  return (u16)(x >> 16);
}
DEV u32 pk2(float a, float b) { return (u32)f2bf(a) | ((u32)f2bf(b) << 16); }
DEV float gelu_f(float x) { return 0.5f * x * (1.0f + erff(x * 0.70710678118654752440f)); }

// ---------------------------------------------------------------- fused convert f32 -> bf16
// Work unit = 8 elems; NONTEMPORAL loads on the read-once f32 source (bypass
// L3 allocation for the read stream; keep L3 for the bf16 writes the GEMMs
// re-read).  r13-measured: drops cvt from ~90us to <63us.
__global__ void cvt5_k(const float* __restrict__ s0, const float* __restrict__ s1,
                       const float* __restrict__ s2, const float* __restrict__ s3,
                       const float* __restrict__ s4,
                       u16* __restrict__ d0, u16* __restrict__ d1, u16* __restrict__ d2,
                       u16* __restrict__ d3, u16* __restrict__ d4,
                       int n0, int n1, int n2, int n3, int n4) {
  const int total = n0 + n1 + n2 + n3 + n4;   // in 8-elem units
  for (int i = blockIdx.x * 256 + threadIdx.x; i < total; i += gridDim.x * 256) {
    const float* s; u16* d; int j = i;
    if (j < n0) { s = s0; d = d0; }
    else {
      j -= n0;
      if (j < n1) { s = s1; d = d1; }
      else {
        j -= n1;
        if (j < n2) { s = s2; d = d2; }
        else {
          j -= n2;
          if (j < n3) { s = s3; d = d3; }
          else { j -= n3; s = s4; d = d4; }
        }
      }
    }
    f32x4 a = __builtin_nontemporal_load((const f32x4*)s + j * 2);
    f32x4 b = __builtin_nontemporal_load((const f32x4*)s + j * 2 + 1);
    uint4 o;
    o.x = pk2(a[0], a[1]); o.y = pk2(a[2], a[3]);
    o.z = pk2(b[0], b[1]); o.w = pk2(b[2], b[3]);
    ((uint4*)d)[j] = o;
  }
}

// transpose h0_w1 (64,1024) -> (1024,64) f32
__global__ void w1t_k(const float* __restrict__ w1, float* __restrict__ w1t) {
  int i = blockIdx.x * 256 + threadIdx.x;
  if (i < 64 * 1024) {
    int o = i >> 10, c = i & 1023;
    w1t[c * 64 + o] = w1[i];
  }
}

// ---------------------------------------------------------------- LayerNorm (row per WAVE)
// 4 rows/block, row in registers, shfl_xor reduce, no LDS.  (r12-proven)
template<int DIM, int OUTM, int INBF>
__global__ __launch_bounds__(256) void ln_k(const void* __restrict__ inp,
                                            const float* __restrict__ g,
                                            const float* __restrict__ b,
                                            void* __restrict__ outp) {
  constexpr int NG = DIM / 512;   // 8-elem groups per lane
  const int w = threadIdx.x >> 6, lane = threadIdx.x & 63;
  const int row = blockIdx.x * 4 + w;
  float v[NG * 8];
  if (INBF == 1) {
    const u16* in = (const u16*)inp + (size_t)row * DIM;
#pragma unroll
    for (int i = 0; i < NG; ++i) {
      uint4 u = ((const uint4*)in)[i * 64 + lane];
      const u16* e = (const u16*)&u;
#pragma unroll
      for (int t = 0; t < 8; ++t) v[i * 8 + t] = bf2f(e[t]);
    }
  } else {
    const float* in = (const float*)inp + (size_t)row * DIM;
#pragma unroll
    for (int i = 0; i < NG; ++i)
#pragma unroll
      for (int h = 0; h < 2; ++h) {
        float4 f = ((const float4*)in)[i * 128 + h * 64 + lane];
        v[i * 8 + h * 4 + 0] = f.x; v[i * 8 + h * 4 + 1] = f.y;
        v[i * 8 + h * 4 + 2] = f.z; v[i * 8 + h * 4 + 3] = f.w;
      }
  }
  float s = 0.f, s2 = 0.f;
#pragma unroll
  for (int t = 0; t < NG * 8; ++t) { s += v[t]; s2 += v[t] * v[t]; }
#pragma unroll
  for (int d = 1; d < 64; d <<= 1) { s += __shfl_xor(s, d); s2 += __shfl_xor(s2, d); }
  const float mean = s / DIM;
  const float rstd = rsqrtf(s2 / DIM - mean * mean + 1e-5f);

  if (INBF == 1) {
#pragma unroll
    for (int i = 0; i < NG; ++i) {
      const int u8 = i * 64 + lane;
      float o[8];
#pragma unroll
      for (int h = 0; h < 2; ++h) {
        float4 gv = ((const float4*)g)[u8 * 2 + h];
        float4 bv = ((const float4*)b)[u8 * 2 + h];
        o[h * 4 + 0] = (v[i * 8 + h * 4 + 0] - mean) * rstd * gv.x + bv.x;
        o[h * 4 + 1] = (v[i * 8 + h * 4 + 1] - mean) * rstd * gv.y + bv.y;
        o[h * 4 + 2] = (v[i * 8 + h * 4 + 2] - mean) * rstd * gv.z + bv.z;
        o[h * 4 + 3] = (v[i * 8 + h * 4 + 3] - mean) * rstd * gv.w + bv.w;
      }
      if (OUTM == 0) {
        uint4 u;
        u.x = pk2(o[0], o[1]); u.y = pk2(o[2], o[3]);
        u.z = pk2(o[4], o[5]); u.w = pk2(o[6], o[7]);
        ((uint4*)((u16*)outp + (size_t)row * DIM))[u8] = u;
      } else {
        float* orow = (float*)outp + (size_t)row * DIM;
#pragma unroll
        for (int h = 0; h < 2; ++h)
          ((float4*)orow)[u8 * 2 + h] =
              make_float4(o[h * 4 + 0], o[h * 4 + 1], o[h * 4 + 2], o[h * 4 + 3]);
      }
    }
  } else {
#pragma unroll
    for (int i = 0; i < NG; ++i) {
#pragma unroll
      for (int h = 0; h < 2; ++h) {
        const int u4 = i * 128 + h * 64 + lane;
        float4 gv = ((const float4*)g)[u4];
        float4 bv = ((const float4*)b)[u4];
        float o0 = (v[i * 8 + h * 4 + 0] - mean) * rstd * gv.x + bv.x;
        float o1 = (v[i * 8 + h * 4 + 1] - mean) * rstd * gv.y + bv.y;
        float o2 = (v[i * 8 + h * 4 + 2] - mean) * rstd * gv.z + bv.z;
        float o3 = (v[i * 8 + h * 4 + 3] - mean) * rstd * gv.w + bv.w;
        if (OUTM == 0) {
          ushort4 u;
          u.x = f2bf(o0); u.y = f2bf(o1); u.z = f2bf(o2); u.w = f2bf(o3);
          ((ushort4*)((u16*)outp + (size_t)row * DIM))[u4] = u;
        } else {
          ((float4*)((float*)outp + (size_t)row * DIM))[u4] = make_float4(o0, o1, o2, o3);
        }
      }
    }
  }
}

// ---------------------------------------------------------------- bf16 NT GEMM + epilogues
// C[m,n] = sum_k A[m,k] * B[n,k] + bias[n]    (r3/r8-proven structure, FROZEN)
// 512 threads (8 waves), BM=128, BN in {128,64}, BK=64, double-buffered LDS.
// EPI (all bf16 out): 0 = gelu, 1 = plain, 2 = residual add in-place, 3 = relu
template<int EPI, int BN>
__global__ __launch_bounds__(512, BN == 64 ? 6 : 4)
void gemm_bt(const u16* __restrict__ A,
             const u16* __restrict__ B,
             const float* __restrict__ bias,
             u16* __restrict__ Cb,
             int N, int K, int nx) {
  constexpr int WC = BN / 32;
  constexpr int MR = (128 * WC / 8) / 16;
  __shared__ u16 As[2][128 * 64];
  __shared__ u16 Bs[2][BN * 64];
  const int tid = threadIdx.x;
  const int nwg = gridDim.x;
  const int bid = blockIdx.x;
  const int swz = (bid & 7) * (nwg >> 3) + (bid >> 3);
  const int by = swz / nx, bx = swz - by * nx;
  const int brow = by * 128, bcol = bx * BN;
  const int lane = tid & 63, w = tid >> 6;
  const int wr = (w / WC) * (MR * 16), wc = (w % WC) * 32;
  const int fr = lane & 15, fg = lane >> 4;
  const int swb = (fr & 7) << 4;
  const int ldr = lane >> 3;
  const int lc8 = lane & 7;
  const int cs8 = (lc8 ^ ldr) * 8;

  const u16* Ab = A + (size_t)(brow + ldr) * K + cs8;
  const u16* Bb = B + (size_t)(bcol + ldr) * K + cs8;

  f32x4 acc[MR][2];
  const f32x4 z = {0.f, 0.f, 0.f, 0.f};
#pragma unroll
  for (int m = 0; m < MR; ++m) { acc[m][0] = z; acc[m][1] = z; }

  auto stage = [&](int kt, int buf) {
    const int k0 = kt << 6;
#pragma unroll
    for (int i = 0; i < 2; ++i) {
      const int c = i * 8 + w;
      __builtin_amdgcn_global_load_lds(GPTR(Ab + (size_t)c * 8 * K + k0),
                                       LPTR(&As[buf][c * 512 + lane * 8]), 16, 0, 0);
    }
#pragma unroll
    for (int i = 0; i < BN / 64; ++i) {
      const int c = i * 8 + w;
      __builtin_amdgcn_global_load_lds(GPTR(Bb + (size_t)c * 8 * K + k0),
                                       LPTR(&Bs[buf][c * 512 + lane * 8]), 16, 0, 0);
    }
  };

  stage(0, 0);
  const int nkt = K >> 6;
  for (int kt = 0; kt < nkt; ++kt) {
    const int buf = kt & 1;
    asm volatile("s_waitcnt vmcnt(0)" ::: "memory");
    __builtin_amdgcn_s_barrier();
    __builtin_amdgcn_sched_barrier(0);
    if (kt + 1 < nkt) stage(kt + 1, buf ^ 1);
    const char* Asb = (const char*)&As[buf][0];
    const char* Bsb = (const char*)&Bs[buf][0];
    __builtin_amdgcn_s_setprio(1);
#pragma unroll
    for (int ks = 0; ks < 2; ++ks) {
      bf16x8 af[MR], bfr[2];
      const int cb = (ks * 64 + fg * 16) ^ swb;
#pragma unroll
      for (int m = 0; m < MR; ++m)
        af[m] = *(const bf16x8*)(Asb + (wr + m * 16 + fr) * 128 + cb);
#pragma unroll
      for (int n = 0; n < 2; ++n)
        bfr[n] = *(const bf16x8*)(Bsb + (wc + n * 16 + fr) * 128 + cb);
#pragma unroll
      for (int m = 0; m < MR; ++m)
#pragma unroll
        for (int n = 0; n < 2; ++n)
          acc[m][n] = __builtin_amdgcn_mfma_f32_16x16x32_bf16(af[m], bfr[n], acc[m][n], 0, 0, 0);
    }
    __builtin_amdgcn_s_setprio(0);
  }

#pragma unroll
  for (int n = 0; n < 2; ++n) {
    const int col = bcol + wc + n * 16 + fr;
    const float bv = bias[col];
#pragma unroll
    for (int m = 0; m < MR; ++m) {
      const int row0 = brow + wr + m * 16 + fg * 4;
#pragma unroll
      for (int j = 0; j < 4; ++j) {
        float v = acc[m][n][j] + bv;
        const size_t idx = (size_t)(row0 + j) * N + col;
        if (EPI == 0) Cb[idx] = f2bf(gelu_f(v));
        else if (EPI == 1) Cb[idx] = f2bf(v);
        else if (EPI == 2) Cb[idx] = f2bf(bf2f(Cb[idx]) + v);
        else Cb[idx] = f2bf(fmaxf(v, 0.f));
      }
    }
  }
}

// ---------------------------------------------------------------- MFMA attention (r11-proven)
__global__ __launch_bounds__(128) void attn_k(const u16* __restrict__ qkv,
                                              u16* __restrict__ o) {
  __shared__ u16 lds[2][12672];   // per wave: Vt[128][72] (9216) + P[48][72] (3456)
  const int tid = threadIdx.x, w = tid >> 6, l = tid & 63;
  const int b = blockIdx.x >> 2, hp = blockIdx.x & 3;
  const int h = hp * 2 + w;
  u16* Vt = &lds[w][0];
  u16* P  = &lds[w][9216];
  const int fr = l & 15, fg = l >> 4;
  const size_t qbase = (size_t)b * 36 * 3072 + h * 128;
  const size_t kbase = qbase + 1024;
  const size_t vbase = qbase + 2048;

  for (int i = l; i < 1584; i += 64) {
    uint4 zz = {0u, 0u, 0u, 0u};
    *(uint4*)&lds[w][i * 8] = zz;
  }

  for (int i = l; i < 576; i += 64) {
    const int k = i >> 4, nc = (i & 15) * 8;
    uint4 u = *(const uint4*)&qkv[vbase + (size_t)k * 3072 + nc];
    const u16* e = (const u16*)&u;
#pragma unroll
    for (int t = 0; t < 8; ++t) Vt[(nc + t) * 72 + k] = e[t];
  }

  const f32x4 z = {0.f, 0.f, 0.f, 0.f};
  f32x4 S[3][3];
#pragma unroll
  for (int mt = 0; mt < 3; ++mt)
#pragma unroll
    for (int nt = 0; nt < 3; ++nt) S[mt][nt] = z;
#pragma unroll
  for (int ks = 0; ks < 4; ++ks) {
    bf16x8 qa[3], kb[3];
#pragma unroll
    for (int mt = 0; mt < 3; ++mt) {
      const int r = min(mt * 16 + fr, 35);
      qa[mt] = *(const bf16x8*)&qkv[qbase + (size_t)r * 3072 + ks * 32 + fg * 8];
      kb[mt] = *(const bf16x8*)&qkv[kbase + (size_t)r * 3072 + ks * 32 + fg * 8];
    }
#pragma unroll
    for (int mt = 0; mt < 3; ++mt)
#pragma unroll
      for (int nt = 0; nt < 3; ++nt)
        S[mt][nt] = __builtin_amdgcn_mfma_f32_16x16x32_bf16(qa[mt], kb[nt], S[mt][nt], 0, 0, 0);
  }

  const float sc = 0.08838834764831845f;
#pragma unroll
  for (int mt = 0; mt < 3; ++mt) {
#pragma unroll
    for (int j = 0; j < 4; ++j) {
      float v0 = S[mt][0][j] * sc;
      float v1 = S[mt][1][j] * sc;
      float v2 = (fr >= 4) ? -1e30f : S[mt][2][j] * sc;
      float m = fmaxf(fmaxf(v0, v1), v2);
#pragma unroll
      for (int d = 1; d < 16; d <<= 1) m = fmaxf(m, __shfl_xor(m, d));
      float e0 = __expf(v0 - m);
      float e1 = __expf(v1 - m);
      float e2 = (fr >= 4) ? 0.f : __expf(v2 - m);
      float sum = e0 + e1 + e2;
#pragma unroll
      for (int d = 1; d < 16; d <<= 1) sum += __shfl_xor(sum, d);
      const float inv = 1.f / sum;
      const int r = mt * 16 + fg * 4 + j;
      P[r * 72 + fr]      = f2bf(e0 * inv);
      P[r * 72 + 16 + fr] = f2bf(e1 * inv);
      P[r * 72 + 32 + fr] = f2bf(e2 * inv);
    }
  }

#pragma unroll
  for (int g = 0; g < 2; ++g) {
    f32x4 O[3][4];
#pragma unroll
    for (int mt = 0; mt < 3; ++mt)
#pragma unroll
      for (int nt = 0; nt < 4; ++nt) O[mt][nt] = z;
#pragma unroll
    for (int ks = 0; ks < 2; ++ks) {
      bf16x8 pa[3], vb[4];
#pragma unroll
      for (int mt = 0; mt < 3; ++mt)
        pa[mt] = *(const bf16x8*)&P[(mt * 16 + fr) * 72 + ks * 32 + fg * 8];
#pragma unroll
      for (int nt = 0; nt < 4; ++nt)
        vb[nt] = *(const bf16x8*)&Vt[((g * 4 + nt) * 16 + fr) * 72 + ks * 32 + fg * 8];
#pragma unroll
      for (int mt = 0; mt < 3; ++mt)
#pragma unroll
        for (int nt = 0; nt < 4; ++nt)
          O[mt][nt] = __builtin_amdgcn_mfma_f32_16x16x32_bf16(pa[mt], vb[nt], O[mt][nt], 0, 0, 0);
    }
#pragma unroll
    for (int mt = 0; mt < 3; ++mt) {
#pragma unroll
      for (int j = 0; j < 4; ++j) {
        const int r = mt * 16 + fg * 4 + j;
        if (r < 36) {
#pragma unroll
          for (int nt = 0; nt < 4; ++nt)
            o[((size_t)b * 36 + r) * 1024 + h * 128 + g * 64 + nt * 16 + fr] =
                f2bf(O[mt][nt][j]);
        }
      }
    }
  }
}

// ---------------------------------------------------------------- attention-map head (r9-proven)
__global__ __launch_bounds__(256) void h0_k(const u16* __restrict__ xr,
                                            const float* __restrict__ w1t,
                                            const float* __restrict__ b1,
                                            const float* __restrict__ w2,
                                            const float* __restrict__ b2v,
                                            float* __restrict__ full) {
  __shared__ float xs[8][1024];  // 32 KB
  const int t0 = blockIdx.x * 8, tid = threadIdx.x;
#pragma unroll
  for (int i = 0; i < 8; ++i) {
    const int idx = tid + i * 256;
    const int t = idx >> 8, c4 = idx & 255;
    ushort4 u = ((const ushort4*)(xr + (size_t)(t0 + t) * 1024))[c4];
    xs[t][c4 * 4 + 0] = bf2f(u.x);
    xs[t][c4 * 4 + 1] = bf2f(u.y);
    xs[t][c4 * 4 + 2] = bf2f(u.z);
    xs[t][c4 * 4 + 3] = bf2f(u.w);
  }
  __syncthreads();
  const int w = tid >> 6, lane = tid & 63;
  float s0 = 0.f, s1 = 0.f;
  for (int c = 0; c < 1024; ++c) {
    const float wv = w1t[c * 64 + lane];
    s0 = fmaf(xs[w * 2 + 0][c], wv, s0);
    s1 = fmaf(xs[w * 2 + 1][c], wv, s1);
  }
  const float bb = b1[lane], wo = w2[lane];
  float v0 = gelu_f(s0 + bb) * wo;
  float v1 = gelu_f(s1 + bb) * wo;
#pragma unroll
  for (int off = 32; off; off >>= 1) {
    v0 += __shfl_down(v0, off);
    v1 += __shfl_down(v1, off);
  }
  if (lane == 0) {
    full[t0 + w * 2 + 0] = v0 + b2v[0];
    full[t0 + w * 2 + 1] = v1 + b2v[0];
  }
}

__global__ void am2_k(const float* __restrict__ full, const float* __restrict__ temp,
                      float* __restrict__ out) {
  const int i = blockIdx.x * 256 + threadIdx.x;
  if (i < 128 * 36 * 35) {
    const int j = i % 35;
    const int t = i / 35;
    const int p = t % 36;
    const int b = t / 36;
    const int col = j + (j >= p ? 1 : 0);
    const float v = full[b * 36 + col] / temp[0];
    out[i] = 1.f / (1.f + expf(-v));
  }
}

// ---------------------------------------------------------------- launch
extern "C" void kernel_launch(void* const* d_in, const int* in_sizes, int n_in,
                              void* d_out, int out_size, void* d_ws, size_t ws_size,
                              hipStream_t stream) {
  const float* x     = (const float*)d_in[0];
  const float* ln0_g = (const float*)d_in[1];
  const float* ln0_b = (const float*)d_in[2];
  const float* Wred  = (const float*)d_in[3];
  const float* bred  = (const float*)d_in[4];
  const float* h0_w1 = (const float*)d_in[5];
  const float* h0_b1 = (const float*)d_in[6];
  const float* h0_w2 = (const float*)d_in[7];
  const float* h0_b2 = (const float*)d_in[8];
  const float* temp  = (const float*)d_in[9];
  const float* Wqkv  = (const float*)d_in[10];
  const float* bqkv  = (const float*)d_in[11];
  const float* Wo    = (const float*)d_in[12];
  const float* bo    = (const float*)d_in[13];
  const float* ln1_g = (const float*)d_in[14];
  const float* ln1_b = (const float*)d_in[15];
  const float* W1    = (const float*)d_in[16];
  const float* b1    = (const float*)d_in[17];
  const float* W2    = (const float*)d_in[18];
  const float* b2    = (const float*)d_in[19];
  const float* ln2_g = (const float*)d_in[20];
  const float* ln2_b = (const float*)d_in[21];
  const float* lnf_g = (const float*)d_in[22];
  const float* lnf_b = (const float*)d_in[23];

  char* ws = (char*)d_ws;
  size_t off = 0;
  auto alloc = [&](size_t bytes) -> void* {
    void* p = ws + off;
    off += (bytes + 255) & ~(size_t)255;
    return p;
  };
  u16* WredB  = (u16*)alloc((size_t)1024 * 3072 * 2);
  u16* WqkvB  = (u16*)alloc((size_t)6 * 3072 * 1024 * 2);
  u16* WoB    = (u16*)alloc((size_t)6 * 1024 * 1024 * 2);
  u16* W1B    = (u16*)alloc((size_t)6 * 2048 * 1024 * 2);
  u16* W2B    = (u16*)alloc((size_t)6 * 1024 * 2048 * 2);
  float* w1t  = (float*)alloc((size_t)1024 * 64 * 4);
  u16* yb     = (u16*)alloc((size_t)4608 * 1024 * 2);   // residual stream (bf16)
  u16* big    = (u16*)alloc((size_t)4608 * 3072 * 2);   // xn / qkv / f
  u16* nbuf   = (u16*)alloc((size_t)4608 * 1024 * 2);   // ynorm / o
  float* fullb = (float*)alloc((size_t)4608 * 4);

  cvt5_k<<<3072, 256, 0, stream>>>(
      Wred, Wqkv, Wo, W1, W2, WredB, WqkvB, WoB, W1B, W2B,
      (int)(1024 * 3072 / 8), (int)(6 * 3072 * 1024 / 8), (int)(6 * 1024 * 1024 / 8),
      (int)(6 * 2048 * 1024 / 8), (int)(6 * 1024 * 2048 / 8));
  w1t_k<<<64 * 1024 / 256, 256, 0, stream>>>(h0_w1, w1t);

  // dim reduce: xr = gelu(LN0(x) @ Wred^T + bred) -> yb (bf16)
  ln_k<3072, 0, 0><<<1152, 256, 0, stream>>>(x, ln0_g, ln0_b, big);
  gemm_bt<0, 64><<<16 * 36, 512, 0, stream>>>(big, WredB, bred, yb, 1024, 3072, 16);
  // attention maps head
  h0_k<<<576, 256, 0, stream>>>(yb, w1t, h0_b1, h0_w2, h0_b2, fullb);
  am2_k<<<(128 * 36 * 35 + 255) / 256, 256, 0, stream>>>(fullb, temp,
                                                         (float*)d_out + 4608 * 1024);

  for (int l = 0; l < 6; ++l) {
    ln_k<1024, 0, 1><<<1152, 256, 0, stream>>>(yb, ln1_g + l * 1024, ln1_b + l * 1024, nbuf);
    gemm_bt<1, 128><<<24 * 36, 512, 0, stream>>>(nbuf, WqkvB + (size_t)l * 3072 * 1024,
                                                 bqkv + l * 3072, big, 3072, 1024, 24);
    attn_k<<<128 * 4, 128, 0, stream>>>(big, nbuf);
    gemm_bt<2, 64><<<16 * 36, 512, 0, stream>>>(nbuf, WoB + (size_t)l * 1024 * 1024,
                                                bo + l * 1024, yb, 1024, 1024, 16);
    ln_k<1024, 0, 1><<<1152, 256, 0, stream>>>(yb, ln2_g + l * 1024, ln2_b + l * 1024, nbuf);
    gemm_bt<3, 128><<<16 * 36, 512, 0, stream>>>(nbuf, W1B + (size_t)l * 2048 * 1024,
                                                 b1 + l * 2048, big, 2048, 1024, 16);
    gemm_bt<2, 64><<<16 * 36, 512, 0, stream>>>(big, W2B + (size_t)l * 1024 * 2048,
                                                b2 + l * 1024, yb, 1024, 2048, 16);
  }
  ln_k<1024, 1, 1><<<1152, 256, 0, stream>>>(yb, lnf_g, lnf_b, d_out);
}